// Round 1
// baseline (281.080 us; speedup 1.0000x reference)
//
#include <hip/hip_runtime.h>

// Skewed MAE: mean(|p - t| * exp(sign(t - p) * lam(t)))
// With LAMDA_MAX=1, LIM=(0,1), MEDIAN_AGE=0.5 the two lambda ramps are
// identical: lam(t) = 2t - 1 (no branch needed).
// Memory-bound: 268 MB read -> ~43 us floor at 6.3 TB/s.

#define BLOCK 256
#define GRID 2048

__device__ __forceinline__ float skew_elem(float p, float t) {
    float d = p - t;
    float lam = __builtin_fmaf(2.0f, t, -1.0f);     // 2t - 1
    float s = (d < 0.0f) ? lam : -lam;              // sign(t-p)*lam; d==0 -> |d|=0 anyway
    return fabsf(d) * __expf(s);
}

__global__ __launch_bounds__(BLOCK) void skewed_mae_kernel(
        const float4* __restrict__ yp4, const float4* __restrict__ yt4,
        const float* __restrict__ yp, const float* __restrict__ yt,
        float* __restrict__ out, int n4, int n, float inv_n) {
    int tid = blockIdx.x * BLOCK + threadIdx.x;
    int stride = gridDim.x * BLOCK;

    float acc = 0.0f;
    for (int i = tid; i < n4; i += stride) {
        float4 p = yp4[i];
        float4 t = yt4[i];
        acc += skew_elem(p.x, t.x);
        acc += skew_elem(p.y, t.y);
        acc += skew_elem(p.z, t.z);
        acc += skew_elem(p.w, t.w);
    }
    // scalar tail (n % 4 != 0); n = 33554432 -> empty, but stay general
    for (int i = n4 * 4 + tid; i < n; i += stride) {
        acc += skew_elem(yp[i], yt[i]);
    }
    acc *= inv_n;

    // wave-64 reduction
    #pragma unroll
    for (int off = 32; off > 0; off >>= 1)
        acc += __shfl_down(acc, off, 64);

    __shared__ float smem[BLOCK / 64];
    int lane = threadIdx.x & 63;
    int wave = threadIdx.x >> 6;
    if (lane == 0) smem[wave] = acc;
    __syncthreads();

    if (threadIdx.x == 0) {
        float s = 0.0f;
        #pragma unroll
        for (int w = 0; w < BLOCK / 64; ++w) s += smem[w];
        atomicAdd(out, s);   // device-scope by default on CDNA
    }
}

extern "C" void kernel_launch(void* const* d_in, const int* in_sizes, int n_in,
                              void* d_out, int out_size, void* d_ws, size_t ws_size,
                              hipStream_t stream) {
    const float* yp = (const float*)d_in[0];
    const float* yt = (const float*)d_in[1];
    float* out = (float*)d_out;
    int n = in_sizes[0];
    int n4 = n / 4;

    // d_out is poisoned with 0xAA before every timed launch; zero it first.
    hipMemsetAsync(out, 0, sizeof(float), stream);

    skewed_mae_kernel<<<GRID, BLOCK, 0, stream>>>(
        (const float4*)yp, (const float4*)yt, yp, yt, out, n4, n, 1.0f / (float)n);
}

// Round 2
// 277.993 us; speedup vs baseline: 1.0111x; 1.0111x over previous
//
#include <hip/hip_runtime.h>

// Skewed MAE: mean(|p - t| * exp(sign(t - p) * (2t - 1)))
// (Both lambda ramps collapse to lam(t) = 2t-1 for LAMDA_MAX=1, LIM=(0,1),
//  MEDIAN_AGE=0.5.)
//
// R1 post-mortem: VGPR=12 kernel was latency-bound (2 outstanding loads/wave,
// 105 us, 8% VALUBusy, same dur even when fully L3-resident). Fix: unroll x8
// with a separated load phase -> 16 loads in flight per wave.

#define BLOCK 256
#define GRID 2048
#define UNROLL 8

__device__ __forceinline__ float skew_elem(float p, float t) {
    float d = p - t;
    float lam = __builtin_fmaf(2.0f, t, -1.0f);     // 2t - 1
    float s = (d < 0.0f) ? lam : -lam;              // sign(t-p)*lam; d==0 -> |d|=0
    return fabsf(d) * __expf(s);
}

__global__ __launch_bounds__(BLOCK) void skewed_mae_kernel(
        const float4* __restrict__ yp4, const float4* __restrict__ yt4,
        const float* __restrict__ yp, const float* __restrict__ yt,
        float* __restrict__ out, int n4, int n, float inv_n) {
    const int tid = blockIdx.x * BLOCK + threadIdx.x;
    const int stride = GRID * BLOCK;

    float acc = 0.0f;

    // Main unrolled loop: 2*UNROLL independent 16B loads in flight per wave.
    int base = tid;
    for (; base + (UNROLL - 1) * stride < n4; base += UNROLL * stride) {
        float4 p[UNROLL], t[UNROLL];
        #pragma unroll
        for (int k = 0; k < UNROLL; ++k) p[k] = yp4[base + k * stride];
        #pragma unroll
        for (int k = 0; k < UNROLL; ++k) t[k] = yt4[base + k * stride];
        #pragma unroll
        for (int k = 0; k < UNROLL; ++k) {
            acc += skew_elem(p[k].x, t[k].x);
            acc += skew_elem(p[k].y, t[k].y);
            acc += skew_elem(p[k].z, t[k].z);
            acc += skew_elem(p[k].w, t[k].w);
        }
    }
    // Remainder float4 chunks.
    for (; base < n4; base += stride) {
        float4 p = yp4[base];
        float4 t = yt4[base];
        acc += skew_elem(p.x, t.x);
        acc += skew_elem(p.y, t.y);
        acc += skew_elem(p.z, t.z);
        acc += skew_elem(p.w, t.w);
    }
    // Scalar tail (n % 4 != 0); empty for n = 33554432.
    for (int i = n4 * 4 + tid; i < n; i += stride) {
        acc += skew_elem(yp[i], yt[i]);
    }
    acc *= inv_n;

    // wave-64 reduction
    #pragma unroll
    for (int off = 32; off > 0; off >>= 1)
        acc += __shfl_down(acc, off, 64);

    __shared__ float smem[BLOCK / 64];
    int lane = threadIdx.x & 63;
    int wave = threadIdx.x >> 6;
    if (lane == 0) smem[wave] = acc;
    __syncthreads();

    if (threadIdx.x == 0) {
        float s = 0.0f;
        #pragma unroll
        for (int w = 0; w < BLOCK / 64; ++w) s += smem[w];
        atomicAdd(out, s);   // device-scope by default on CDNA
    }
}

extern "C" void kernel_launch(void* const* d_in, const int* in_sizes, int n_in,
                              void* d_out, int out_size, void* d_ws, size_t ws_size,
                              hipStream_t stream) {
    const float* yp = (const float*)d_in[0];
    const float* yt = (const float*)d_in[1];
    float* out = (float*)d_out;
    int n = in_sizes[0];
    int n4 = n / 4;

    // d_out is poisoned with 0xAA before every timed launch; zero it first.
    hipMemsetAsync(out, 0, sizeof(float), stream);

    skewed_mae_kernel<<<GRID, BLOCK, 0, stream>>>(
        (const float4*)yp, (const float4*)yt, yp, yt, out, n4, n, 1.0f / (float)n);
}

// Round 3
// 273.283 us; speedup vs baseline: 1.0285x; 1.0172x over previous
//
#include <hip/hip_runtime.h>

// Skewed MAE: mean(|p - t| * exp(sign(t - p) * (2t - 1)))
// (Both lambda ramps collapse to lam(t) = 2t-1 for LAMDA_MAX=1, LIM=(0,1),
//  MEDIAN_AGE=0.5.)
//
// R2 post-mortem: dur constant at 105us whether inputs are HBM-resident or
// L3-resident (FETCH 131MB vs 64KB) => not BW-bound anywhere. VALUBusy 7%.
// Theory: the 2048 same-address fp32 atomicAdds compile to CAS loops
// (safe-fp-atomics) and serialize at ~50ns each => ~100us constant tail.
// Fix: two-stage reduction via d_ws, zero atomics, fully deterministic.

#define BLOCK 256
#define GRID 2048
#define UNROLL 8

__device__ __forceinline__ float skew_elem(float p, float t) {
    float d = p - t;
    float lam = __builtin_fmaf(2.0f, t, -1.0f);     // 2t - 1
    float s = (d < 0.0f) ? lam : -lam;              // sign(t-p)*lam; d==0 -> |d|=0
    return fabsf(d) * __expf(s);
}

__device__ __forceinline__ float block_reduce(float acc) {
    #pragma unroll
    for (int off = 32; off > 0; off >>= 1)
        acc += __shfl_down(acc, off, 64);
    __shared__ float smem[BLOCK / 64];
    int lane = threadIdx.x & 63;
    int wave = threadIdx.x >> 6;
    if (lane == 0) smem[wave] = acc;
    __syncthreads();
    float s = 0.0f;
    #pragma unroll
    for (int w = 0; w < BLOCK / 64; ++w) s += smem[w];
    return s;   // valid in all threads (cheap; avoids a second sync)
}

__global__ __launch_bounds__(BLOCK) void skewed_mae_stage1(
        const float4* __restrict__ yp4, const float4* __restrict__ yt4,
        const float* __restrict__ yp, const float* __restrict__ yt,
        float* __restrict__ partials, int n4, int n, float inv_n) {
    const int tid = blockIdx.x * BLOCK + threadIdx.x;
    const int stride = GRID * BLOCK;

    float acc = 0.0f;

    int base = tid;
    for (; base + (UNROLL - 1) * stride < n4; base += UNROLL * stride) {
        float4 p[UNROLL], t[UNROLL];
        #pragma unroll
        for (int k = 0; k < UNROLL; ++k) p[k] = yp4[base + k * stride];
        #pragma unroll
        for (int k = 0; k < UNROLL; ++k) t[k] = yt4[base + k * stride];
        #pragma unroll
        for (int k = 0; k < UNROLL; ++k) {
            acc += skew_elem(p[k].x, t[k].x);
            acc += skew_elem(p[k].y, t[k].y);
            acc += skew_elem(p[k].z, t[k].z);
            acc += skew_elem(p[k].w, t[k].w);
        }
    }
    for (; base < n4; base += stride) {
        float4 p = yp4[base];
        float4 t = yt4[base];
        acc += skew_elem(p.x, t.x);
        acc += skew_elem(p.y, t.y);
        acc += skew_elem(p.z, t.z);
        acc += skew_elem(p.w, t.w);
    }
    for (int i = n4 * 4 + tid; i < n; i += stride) {
        acc += skew_elem(yp[i], yt[i]);
    }
    acc *= inv_n;

    float s = block_reduce(acc);
    if (threadIdx.x == 0) partials[blockIdx.x] = s;
}

// Stage 2: one block reduces GRID partials and writes the scalar output.
__global__ __launch_bounds__(BLOCK) void skewed_mae_stage2(
        const float* __restrict__ partials, float* __restrict__ out) {
    float acc = 0.0f;
    #pragma unroll
    for (int k = 0; k < GRID / BLOCK; ++k)
        acc += partials[k * BLOCK + threadIdx.x];
    float s = block_reduce(acc);
    if (threadIdx.x == 0) out[0] = s;
}

extern "C" void kernel_launch(void* const* d_in, const int* in_sizes, int n_in,
                              void* d_out, int out_size, void* d_ws, size_t ws_size,
                              hipStream_t stream) {
    const float* yp = (const float*)d_in[0];
    const float* yt = (const float*)d_in[1];
    float* out = (float*)d_out;
    float* partials = (float*)d_ws;    // GRID floats = 8 KB scratch
    int n = in_sizes[0];
    int n4 = n / 4;

    skewed_mae_stage1<<<GRID, BLOCK, 0, stream>>>(
        (const float4*)yp, (const float4*)yt, yp, yt, partials, n4, n,
        1.0f / (float)n);
    skewed_mae_stage2<<<1, BLOCK, 0, stream>>>(partials, out);
}